// Round 1
// baseline (564.769 us; speedup 1.0000x reference)
//
#include <hip/hip_runtime.h>

#define TOKENS 16384
#define HDIM   4096
#define NEXP   64
#define TPW    8                 // tokens per wave
#define NWAVE  4                 // waves per block
#define TPB    (TPW * NWAVE)     // 32 tokens per block
#define KC     256               // k-elements per staged chunk
#define NSLICE (KC / 4)          // 64 k4-slices per chunk
#define SLICES_PER_WAVE (NSLICE / NWAVE)
#define NCHUNK (HDIM / KC)       // 16

// global -> LDS direct copy, 16B per lane. LDS dest is wave-uniform base +
// lane*16 (linear); global src is per-lane (lane = expert row).
__device__ __forceinline__ void load_lds16(const float* g, float* l) {
  __builtin_amdgcn_global_load_lds(
      (const __attribute__((address_space(1))) void*)g,
      (__attribute__((address_space(3))) void*)l, 16, 0, 0);
}

__global__ __launch_bounds__(256, 2)
void router_main_kernel(const float* __restrict__ hidden,
                        const float* __restrict__ gate,
                        float* __restrict__ out,
                        float* __restrict__ accum) {
  // wt layout: [slice s][expert e][4 consecutive k]  => 64KB
  __shared__ float wt[NSLICE * NEXP * 4];

  const int tid  = threadIdx.x;
  const int lane = tid & 63;          // lane = expert index
  const int wave = tid >> 6;
  const int tok0 = blockIdx.x * TPB + wave * TPW;

  const float* hbase = hidden + (size_t)tok0 * HDIM;
  const float* gbase = gate   + (size_t)lane * HDIM;

  float acc[TPW];
#pragma unroll
  for (int t = 0; t < TPW; ++t) acc[t] = 0.f;

  for (int ch = 0; ch < NCHUNK; ++ch) {
    const int kb = ch * KC;
    __syncthreads();   // previous chunk's compute done before overwrite
#pragma unroll
    for (int j = 0; j < SLICES_PER_WAVE; ++j) {
      const int s = wave * SLICES_PER_WAVE + j;
      // lane l loads gate[l][kb + 4s .. +3] -> wt[s][l][0..3]
      load_lds16(gbase + kb + s * 4, &wt[s * (NEXP * 4)]);
    }
    __syncthreads();   // barrier drains vmcnt -> staging visible

#pragma unroll 4
    for (int s = 0; s < NSLICE; ++s) {
      // lane-contiguous 16B per lane: conflict-free ds_read_b128
      const float4 w = *(const float4*)&wt[s * (NEXP * 4) + lane * 4];
      const float* hk = hbase + kb + s * 4;
#pragma unroll
      for (int t = 0; t < TPW; ++t) {
        const float4 h = *(const float4*)(hk + (size_t)t * HDIM); // uniform addr
        acc[t] = fmaf(h.x, w.x, acc[t]);
        acc[t] = fmaf(h.y, w.y, acc[t]);
        acc[t] = fmaf(h.z, w.z, acc[t]);
        acc[t] = fmaf(h.w, w.w, acc[t]);
      }
    }
  }

  // ---- fused epilogue: per-token top-2, softmax weights, P_i/f_i stats ----
  float* out_w = out;                         // [TOKENS][2] router weights
  float* out_e = out + (size_t)TOKENS * 2;    // [TOKENS][2] expert ids (as float)

  float psum_local = 0.f;   // this lane's (= expert's) sum of softmax probs
  int   cnt_local  = 0;     // this expert's selection count

#pragma unroll
  for (int t = 0; t < TPW; ++t) {
    // wave holds token (tok0+t)'s 64 logits, one per lane. Top-2 butterfly
    // with (value, index) tuples; tie -> lower index (matches jax top_k).
    float v1 = acc[t]; int i1 = lane;
    float v2 = -1e30f; int i2 = 9999;
#pragma unroll
    for (int m = 1; m < 64; m <<= 1) {
      float ov1 = __shfl_xor(v1, m, 64);
      int   oi1 = __shfl_xor(i1, m, 64);
      float ov2 = __shfl_xor(v2, m, 64);
      int   oi2 = __shfl_xor(i2, m, 64);
      const bool  ob  = (ov1 > v1) || (ov1 == v1 && oi1 < i1);
      const float nv1 = ob ? ov1 : v1;
      const int   ni1 = ob ? oi1 : i1;
      const float av  = ob ? v1  : ov1;   // loser of the top race
      const int   ai  = ob ? i1  : oi1;
      const float bv  = ob ? ov2 : v2;    // winner's runner-up
      const int   bi  = ob ? oi2 : i2;
      const bool  ab  = (av > bv) || (av == bv && ai < bi);
      v2 = ab ? av : bv;
      i2 = ab ? ai : bi;
      v1 = nv1; i1 = ni1;
    }

    // full softmax prob for this lane's expert (max = v1, known to all lanes)
    const float el = expf(acc[t] - v1);
    float ssum = el;
#pragma unroll
    for (int m = 1; m < 64; m <<= 1) ssum += __shfl_xor(ssum, m, 64);
    psum_local += el / ssum;
    cnt_local  += (lane == i1) ? 1 : 0;
    cnt_local  += (lane == i2) ? 1 : 0;

    if (lane == 0) {
      const int tok = tok0 + t;
      const float e2 = expf(v2 - v1);
      const float w1 = 1.f / (1.f + e2);
      out_w[tok * 2 + 0] = w1;
      out_w[tok * 2 + 1] = e2 * w1;
      out_e[tok * 2 + 0] = (float)i1;
      out_e[tok * 2 + 1] = (float)i2;
    }
  }

  // ---- block-level reduction of per-expert stats, then one atomic each ----
  __syncthreads();                       // done using wt for weights
  wt[wave * 64 + lane]       = psum_local;
  wt[256 + wave * 64 + lane] = (float)cnt_local;
  __syncthreads();
  if (tid < 64) {
    const float ps = wt[tid] + wt[64 + tid] + wt[128 + tid] + wt[192 + tid];
    const float cs = wt[256 + tid] + wt[320 + tid] + wt[384 + tid] + wt[448 + tid];
    atomicAdd(&accum[tid], ps);        // sum of router probs per expert
    atomicAdd(&accum[64 + tid], cs);   // selection count per expert
  }
}

__global__ void zero_accum_kernel(float* __restrict__ accum) {
  if (threadIdx.x < 128) accum[threadIdx.x] = 0.f;
}

__global__ void router_loss_kernel(const float* __restrict__ accum,
                                   float* __restrict__ out) {
  const int l = threadIdx.x;  // 64 threads
  float term = accum[l] * accum[64 + l];   // P_sum_e * count_e
#pragma unroll
  for (int m = 1; m < 64; m <<= 1) term += __shfl_xor(term, m, 64);
  if (l == 0) {
    const float invN = 1.f / (float)TOKENS;
    out[(size_t)TOKENS * 4] = 0.01f * 64.f * term * invN * invN; // out[65536]
  }
}

extern "C" void kernel_launch(void* const* d_in, const int* in_sizes, int n_in,
                              void* d_out, int out_size, void* d_ws, size_t ws_size,
                              hipStream_t stream) {
  const float* hidden = (const float*)d_in[0];  // [4,4096,4096] f32
  const float* gate   = (const float*)d_in[1];  // [64,4096] f32
  float* out   = (float*)d_out;                 // 32768 w + 32768 idx + 1 loss
  float* accum = (float*)d_ws;                  // 128 floats of scratch

  zero_accum_kernel<<<1, 128, 0, stream>>>(accum);
  router_main_kernel<<<TOKENS / TPB, 256, 0, stream>>>(hidden, gate, out, accum);
  router_loss_kernel<<<1, 64, 0, stream>>>(accum, out);
}

// Round 2
// 284.535 us; speedup vs baseline: 1.9849x; 1.9849x over previous
//
#include <hip/hip_runtime.h>

#define TOKENS 16384
#define HDIM   4096
#define KC     64                // k per chunk
#define NSL    (KC / 4)          // 16 4-k slices
#define TPB    32                // tokens per block
#define NCH    (HDIM / KC)       // 64 chunks

// global->LDS direct copy, 16B/lane. LDS dest is wave-uniform base + lane*16
// (linear); all swizzling is done on the per-lane GLOBAL source address and
// mirrored on the LDS read side (both-sides-or-neither rule).
__device__ __forceinline__ void load_lds16(const float* g, float* l) {
  __builtin_amdgcn_global_load_lds(
      (const __attribute__((address_space(1))) void*)g,
      (__attribute__((address_space(3))) void*)l, 16, 0, 0);
}

__global__ __launch_bounds__(128, 3)
void router_main_kernel(const float* __restrict__ hidden,
                        const float* __restrict__ gate,
                        float* __restrict__ out,
                        float* __restrict__ accum) {
  // wt unit u = e*16+su (16B units): gate[e][kb + (su^(e&7))*4 ..+3]  (16 KB)
  // ht unit u = t*16+su           : hidden[tok0+t][kb + (su^(t&7))*4] ( 8 KB)
  __shared__ float wt[NSL * 64 * 4];
  __shared__ float ht[TPB * KC];

  const int tid  = threadIdx.x;
  const int lane = tid & 63;
  const int wave = tid >> 6;         // 0..1
  const int g    = lane >> 3;        // token group 0..7
  const int e    = lane & 7;         // expert-lane 0..7 (owns experts e+8j)
  const int tok0 = blockIdx.x * TPB;
  const int t0   = wave * 16 + g * 2;  // this lane's first token (of 2)

  // ---- chunk-invariant staging addresses ----
  int wsrc[8]; float* wdst[8];
#pragma unroll
  for (int l = 0; l < 8; ++l) {
    const int ub = (wave * 8 + l) * 64;
    const int u  = ub + lane;
    const int es = u >> 4, su = u & 15;
    wsrc[l] = es * HDIM + ((su ^ (es & 7)) << 2);
    wdst[l] = &wt[ub * 4];
  }
  int hsrc[4]; float* hdst[4];
#pragma unroll
  for (int l = 0; l < 4; ++l) {
    const int ub = (wave * 4 + l) * 64;
    const int u  = ub + lane;
    const int t  = u >> 4, su = u & 15;
    hsrc[l] = (tok0 + t) * HDIM + ((su ^ (t & 7)) << 2);
    hdst[l] = &ht[ub * 4];
  }

  float acc0[8], acc1[8];
#pragma unroll
  for (int j = 0; j < 8; ++j) { acc0[j] = 0.f; acc1[j] = 0.f; }

  const char* wp  = (const char*)wt + e * 256;          // + j*2048 + ((s^e)<<4)
  const char* hp0 = (const char*)ht + (t0 + 0) * 256;
  const char* hp1 = (const char*)ht + (t0 + 1) * 256;
  const int   x0  = (t0 + 0) & 7, x1 = (t0 + 1) & 7;

  for (int ch = 0; ch < NCH; ++ch) {
    const int kb = ch * KC;
    __syncthreads();                      // previous chunk fully consumed
#pragma unroll
    for (int l = 0; l < 8; ++l) load_lds16(gate + wsrc[l] + kb, wdst[l]);
#pragma unroll
    for (int l = 0; l < 4; ++l) load_lds16(hidden + hsrc[l] + kb, hdst[l]);
    __syncthreads();                      // barrier drains vmcnt -> tiles ready

#pragma unroll
    for (int s = 0; s < NSL; ++s) {
      const float4 h0 = *(const float4*)(hp0 + ((s ^ x0) << 4));
      const float4 h1 = *(const float4*)(hp1 + ((s ^ x1) << 4));
      const int wo = (s ^ e) << 4;
#pragma unroll
      for (int j = 0; j < 8; ++j) {
        const float4 w = *(const float4*)(wp + j * 2048 + wo);
        acc0[j] = fmaf(h0.x, w.x, acc0[j]);
        acc0[j] = fmaf(h0.y, w.y, acc0[j]);
        acc0[j] = fmaf(h0.z, w.z, acc0[j]);
        acc0[j] = fmaf(h0.w, w.w, acc0[j]);
        acc1[j] = fmaf(h1.x, w.x, acc1[j]);
        acc1[j] = fmaf(h1.y, w.y, acc1[j]);
        acc1[j] = fmaf(h1.z, w.z, acc1[j]);
        acc1[j] = fmaf(h1.w, w.w, acc1[j]);
      }
    }
  }

  // ---- fused epilogue: top-2 + softmax + per-expert stats ----
  float psum[8]; int cnt[8];
#pragma unroll
  for (int j = 0; j < 8; ++j) { psum[j] = 0.f; cnt[j] = 0; }

  float* out_w = out;                        // [TOKENS][2] weights
  float* out_e = out + (size_t)TOKENS * 2;   // [TOKENS][2] indices (as float)

  auto epilogue = [&](const float (&a)[8], int tt) {
    const int tok = tok0 + t0 + tt;
    // in-lane top-2 over this lane's 8 experts (ascending index => tie->lower)
    float v1 = a[0]; int i1 = e;
    float v2 = -3.4e38f; int i2 = 1 << 30;
#pragma unroll
    for (int j = 1; j < 8; ++j) {
      const float v = a[j]; const int ix = e + 8 * j;
      if (v > v1)      { v2 = v1; i2 = i1; v1 = v; i1 = ix; }
      else if (v > v2) { v2 = v;  i2 = ix; }
    }
    // merge across the 8 expert-lanes of this token group (xor 1,2,4)
#pragma unroll
    for (int m = 1; m < 8; m <<= 1) {
      const float ov1 = __shfl_xor(v1, m, 64); const int oi1 = __shfl_xor(i1, m, 64);
      const float ov2 = __shfl_xor(v2, m, 64); const int oi2 = __shfl_xor(i2, m, 64);
      const bool  ob  = (ov1 > v1) || (ov1 == v1 && oi1 < i1);
      const float lv  = ob ? v1  : ov1;  const int li  = ob ? i1  : oi1; // loser
      const float rv  = ob ? ov2 : v2;   const int ri  = ob ? oi2 : i2;  // winner's #2
      v1 = ob ? ov1 : v1; i1 = ob ? oi1 : i1;
      const bool  ab  = (lv > rv) || (lv == rv && li < ri);
      v2 = ab ? lv : rv;  i2 = ab ? li : ri;
    }
    // full softmax prob mass for this lane's 8 experts (v1 = true max)
    float el[8]; float ls = 0.f;
#pragma unroll
    for (int j = 0; j < 8; ++j) { el[j] = expf(a[j] - v1); ls += el[j]; }
#pragma unroll
    for (int m = 1; m < 8; m <<= 1) ls += __shfl_xor(ls, m, 64);
    const float inv = 1.f / ls;
#pragma unroll
    for (int j = 0; j < 8; ++j) {
      psum[j] += el[j] * inv;
      cnt[j]  += (i1 == e + 8 * j) + (i2 == e + 8 * j);
    }
    if (e == 0) {
      const float e2 = expf(v2 - v1);
      const float w1 = 1.f / (1.f + e2);
      out_w[tok * 2 + 0] = w1;
      out_w[tok * 2 + 1] = e2 * w1;
      out_e[tok * 2 + 0] = (float)i1;
      out_e[tok * 2 + 1] = (float)i2;
    }
  };
  epilogue(acc0, 0);
  epilogue(acc1, 1);

  // ---- block reduction of per-expert stats, one atomic per expert ----
  __syncthreads();
  float* sb = wt;   // reuse: [128 threads][8] psum, then [128][8] cnt
#pragma unroll
  for (int j = 0; j < 8; ++j) {
    sb[tid * 8 + j]        = psum[j];
    sb[1024 + tid * 8 + j] = (float)cnt[j];
  }
  __syncthreads();
  if (tid < 64) {
    const int es = tid & 7, js = tid >> 3;
    float ps = 0.f, cs = 0.f;
    for (int r = 0; r < 16; ++r) {
      ps += sb[(r * 8 + es) * 8 + js];
      cs += sb[1024 + (r * 8 + es) * 8 + js];
    }
    atomicAdd(&accum[tid], ps);
    atomicAdd(&accum[64 + tid], cs);
  }
}

__global__ void zero_accum_kernel(float* __restrict__ accum) {
  if (threadIdx.x < 128) accum[threadIdx.x] = 0.f;
}

__global__ void router_loss_kernel(const float* __restrict__ accum,
                                   float* __restrict__ out) {
  const int l = threadIdx.x;  // 64 threads
  float term = accum[l] * accum[64 + l];   // P_sum_e * count_e
#pragma unroll
  for (int m = 1; m < 64; m <<= 1) term += __shfl_xor(term, m, 64);
  if (l == 0) {
    const float invN = 1.f / (float)TOKENS;
    out[(size_t)TOKENS * 4] = 0.01f * 64.f * term * invN * invN;
  }
}

extern "C" void kernel_launch(void* const* d_in, const int* in_sizes, int n_in,
                              void* d_out, int out_size, void* d_ws, size_t ws_size,
                              hipStream_t stream) {
  const float* hidden = (const float*)d_in[0];  // [4,4096,4096] f32
  const float* gate   = (const float*)d_in[1];  // [64,4096] f32
  float* out   = (float*)d_out;                 // 32768 w + 32768 idx + 1 loss
  float* accum = (float*)d_ws;                  // 128 floats scratch

  zero_accum_kernel<<<1, 128, 0, stream>>>(accum);
  router_main_kernel<<<TOKENS / TPB, 128, 0, stream>>>(hidden, gate, out, accum);
  router_loss_kernel<<<1, 64, 0, stream>>>(accum, out);
}

// Round 3
// 178.383 us; speedup vs baseline: 3.1660x; 1.5951x over previous
//
#include <hip/hip_runtime.h>

#define TOKENS 16384
#define HDIM   4096
#define KHALF  2048               // K per wave (2 waves split K)

typedef __attribute__((ext_vector_type(8))) short bf16x8;
typedef __attribute__((ext_vector_type(4))) float f32x4;

union PK { int i[4]; bf16x8 v; };

// Split 8 fp32 into hi/mid/lo bf16 parts by exact truncation.
// hi = x&m (exact); r = x-hi (exact); mid = r&m; r2 = r-mid (exact); lo = trunc(r2).
__device__ __forceinline__ void conv8(const float4 a, const float4 b,
                                      bf16x8& ph, bf16x8& pm, bf16x8& pl) {
  float e[8] = {a.x, a.y, a.z, a.w, b.x, b.y, b.z, b.w};
  unsigned int hb[8], mb[8], lb[8];
#pragma unroll
  for (int i = 0; i < 8; ++i) {
    const unsigned int xb = __float_as_uint(e[i]);
    hb[i] = xb & 0xFFFF0000u;
    const float r = e[i] - __uint_as_float(hb[i]);
    const unsigned int rb = __float_as_uint(r);
    mb[i] = rb & 0xFFFF0000u;
    const float r2 = r - __uint_as_float(mb[i]);
    lb[i] = __float_as_uint(r2);
  }
  PK h, m, l;
#pragma unroll
  for (int j = 0; j < 4; ++j) {
    h.i[j] = (int)((hb[2*j] >> 16) | (hb[2*j+1] & 0xFFFF0000u));
    m.i[j] = (int)((mb[2*j] >> 16) | (mb[2*j+1] & 0xFFFF0000u));
    l.i[j] = (int)((lb[2*j] >> 16) | (lb[2*j+1] & 0xFFFF0000u));
  }
  ph = h.v; pm = m.v; pl = l.v;
}

__device__ __forceinline__ void mfma6(const bf16x8 ah, const bf16x8 am, const bf16x8 al,
                                      const bf16x8 bh, const bf16x8 bm, const bf16x8 bl,
                                      f32x4& acc) {
  acc = __builtin_amdgcn_mfma_f32_16x16x32_bf16(ah, bh, acc, 0, 0, 0);
  acc = __builtin_amdgcn_mfma_f32_16x16x32_bf16(am, bh, acc, 0, 0, 0);
  acc = __builtin_amdgcn_mfma_f32_16x16x32_bf16(ah, bm, acc, 0, 0, 0);
  acc = __builtin_amdgcn_mfma_f32_16x16x32_bf16(al, bh, acc, 0, 0, 0);
  acc = __builtin_amdgcn_mfma_f32_16x16x32_bf16(ah, bl, acc, 0, 0, 0);
  acc = __builtin_amdgcn_mfma_f32_16x16x32_bf16(am, bm, acc, 0, 0, 0);
}

__device__ __forceinline__ float4 L(const float* p) {
  return *reinterpret_cast<const float4*>(p);
}

__global__ __launch_bounds__(128, 2)
void router_main_kernel(const float* __restrict__ hidden,
                        const float* __restrict__ gate,
                        float* __restrict__ out,
                        float* __restrict__ accum) {
  __shared__ f32x4 comb[256];     // 64 lanes x 4 n-tiles from wave 1

  const int tid   = threadIdx.x;
  const int lane  = tid & 63;
  const int wave  = tid >> 6;       // 0..1: K-half
  const int col16 = lane & 15;      // MFMA row/col within 16
  const int kq    = lane >> 4;      // k quarter-block
  const int tok0  = blockIdx.x * 16;
  const int kh    = wave * KHALF;

  // A: lane holds token (tok0+col16), k = kh + kq*8 + i   (+32 per chunk)
  const float* aP = hidden + (size_t)(tok0 + col16) * HDIM + kh + kq * 8;
  // B: lane holds expert (nt*16+col16), same k rule
  const float* bP = gate + (size_t)col16 * HDIM + kh + kq * 8;
  const size_t ntStride = (size_t)16 * HDIM;

  f32x4 acc[4];
#pragma unroll
  for (int nt = 0; nt < 4; ++nt) acc[nt] = (f32x4){0.f, 0.f, 0.f, 0.f};

  float4 a0[4], a1[4], b0[8], b1[8];
  // prologue: A pair 0 (chunks 0,1), B chunk 0
  a0[0] = L(aP + 0);  a0[1] = L(aP + 4);
  a0[2] = L(aP + 32); a0[3] = L(aP + 36);
#pragma unroll
  for (int nt = 0; nt < 4; ++nt) {
    b0[2*nt]   = L(bP + nt * ntStride + 0);
    b0[2*nt+1] = L(bP + nt * ntStride + 4);
  }

  auto chunk = [&](const float4 A0, const float4 A1, const float4* B) {
    bf16x8 ah, am, al;
    conv8(A0, A1, ah, am, al);
#pragma unroll
    for (int nt = 0; nt < 4; ++nt) {
      bf16x8 bh, bm, bl;
      conv8(B[2*nt], B[2*nt+1], bh, bm, bl);
      mfma6(ah, am, al, bh, bm, bl, acc[nt]);
    }
  };

  for (int p = 0; p < 32; ++p) {          // p = pair of 32-k chunks
    const int k0 = p * 64;
    if (p + 1 < 32) {                      // prefetch A pair p+1 (2 chunks deep)
      a1[0] = L(aP + k0 + 64); a1[1] = L(aP + k0 + 68);
      a1[2] = L(aP + k0 + 96); a1[3] = L(aP + k0 + 100);
    }
#pragma unroll
    for (int nt = 0; nt < 4; ++nt) {       // prefetch B chunk 2p+1
      b1[2*nt]   = L(bP + nt * ntStride + k0 + 32);
      b1[2*nt+1] = L(bP + nt * ntStride + k0 + 36);
    }
    chunk(a0[0], a0[1], b0);               // compute chunk 2p
    if (p + 1 < 32) {
#pragma unroll
      for (int nt = 0; nt < 4; ++nt) {     // prefetch B chunk 2p+2
        b0[2*nt]   = L(bP + nt * ntStride + k0 + 64);
        b0[2*nt+1] = L(bP + nt * ntStride + k0 + 68);
      }
    }
    chunk(a0[2], a0[3], b1);               // compute chunk 2p+1
    a0[0] = a1[0]; a0[1] = a1[1]; a0[2] = a1[2]; a0[3] = a1[3];
  }

  // ---- combine K-halves: wave 1 -> LDS, wave 0 reduces ----
  if (wave == 1) {
#pragma unroll
    for (int nt = 0; nt < 4; ++nt) comb[lane * 4 + nt] = acc[nt];
  }
  __syncthreads();
  if (wave == 0) {
#pragma unroll
    for (int nt = 0; nt < 4; ++nt) acc[nt] += comb[lane * 4 + nt];

    // acc[nt][r] = logit[token tok0 + kq*4 + r][expert nt*16 + col16]
    float* out_w = out;
    float* out_e = out + (size_t)TOKENS * 2;
    float psum[4] = {0.f, 0.f, 0.f, 0.f};
    float cnt[4]  = {0.f, 0.f, 0.f, 0.f};

#pragma unroll
    for (int r = 0; r < 4; ++r) {
      const int tok = tok0 + kq * 4 + r;
      // in-lane top-2 over the 4 n-tiles (ascending index => tie->lower)
      float v1 = acc[0][r]; int i1 = col16;
      float v2 = -3.4e38f;  int i2 = 1 << 30;
#pragma unroll
      for (int nt = 1; nt < 4; ++nt) {
        const float v = acc[nt][r]; const int ix = nt * 16 + col16;
        if (v > v1)      { v2 = v1; i2 = i1; v1 = v; i1 = ix; }
        else if (v > v2) { v2 = v;  i2 = ix; }
      }
      // butterfly across the 16 lanes of this token group
#pragma unroll
      for (int m = 1; m < 16; m <<= 1) {
        const float ov1 = __shfl_xor(v1, m, 64); const int oi1 = __shfl_xor(i1, m, 64);
        const float ov2 = __shfl_xor(v2, m, 64); const int oi2 = __shfl_xor(i2, m, 64);
        const bool  ob  = (ov1 > v1) || (ov1 == v1 && oi1 < i1);
        const float lv  = ob ? v1  : ov1;  const int li = ob ? i1  : oi1;
        const float rv  = ob ? ov2 : v2;   const int ri = ob ? oi2 : i2;
        v1 = ob ? ov1 : v1; i1 = ob ? oi1 : i1;
        const bool  ab  = (lv > rv) || (lv == rv && li < ri);
        v2 = ab ? lv : rv;  i2 = ab ? li : ri;
      }
      // full softmax over 64 experts (v1 = true max, same in all 16 lanes)
      float el[4], ls = 0.f;
#pragma unroll
      for (int nt = 0; nt < 4; ++nt) { el[nt] = expf(acc[nt][r] - v1); ls += el[nt]; }
#pragma unroll
      for (int m = 1; m < 16; m <<= 1) ls += __shfl_xor(ls, m, 64);
      const float inv = 1.f / ls;
#pragma unroll
      for (int nt = 0; nt < 4; ++nt) {
        psum[nt] += el[nt] * inv;
        cnt[nt]  += (i1 == nt * 16 + col16) + (i2 == nt * 16 + col16);
      }
      if (col16 == 0) {
        const float e2 = expf(v2 - v1);
        const float w1 = 1.f / (1.f + e2);
        out_w[tok * 2 + 0] = w1;
        out_w[tok * 2 + 1] = e2 * w1;
        out_e[tok * 2 + 0] = (float)i1;
        out_e[tok * 2 + 1] = (float)i2;
      }
    }
    // reduce per-expert stats across the 4 token groups (lanes l, l^16, l^32)
#pragma unroll
    for (int nt = 0; nt < 4; ++nt) {
      psum[nt] += __shfl_xor(psum[nt], 16, 64);
      psum[nt] += __shfl_xor(psum[nt], 32, 64);
      cnt[nt]  += __shfl_xor(cnt[nt], 16, 64);
      cnt[nt]  += __shfl_xor(cnt[nt], 32, 64);
    }
    if (lane < 16) {
#pragma unroll
      for (int nt = 0; nt < 4; ++nt) {
        atomicAdd(&accum[nt * 16 + lane], psum[nt]);
        atomicAdd(&accum[64 + nt * 16 + lane], cnt[nt]);
      }
    }
  }
}

__global__ void zero_accum_kernel(float* __restrict__ accum) {
  if (threadIdx.x < 128) accum[threadIdx.x] = 0.f;
}

__global__ void router_loss_kernel(const float* __restrict__ accum,
                                   float* __restrict__ out) {
  const int l = threadIdx.x;  // 64 threads
  float term = accum[l] * accum[64 + l];   // P_sum_e * count_e
#pragma unroll
  for (int m = 1; m < 64; m <<= 1) term += __shfl_xor(term, m, 64);
  if (l == 0) {
    const float invN = 1.f / (float)TOKENS;
    out[(size_t)TOKENS * 4] = 0.01f * 64.f * term * invN * invN;
  }
}

extern "C" void kernel_launch(void* const* d_in, const int* in_sizes, int n_in,
                              void* d_out, int out_size, void* d_ws, size_t ws_size,
                              hipStream_t stream) {
  const float* hidden = (const float*)d_in[0];  // [4,4096,4096] f32
  const float* gate   = (const float*)d_in[1];  // [64,4096] f32
  float* out   = (float*)d_out;                 // 32768 w + 32768 idx + 1 loss
  float* accum = (float*)d_ws;                  // 128 floats scratch

  zero_accum_kernel<<<1, 128, 0, stream>>>(accum);
  router_main_kernel<<<TOKENS / 16, 128, 0, stream>>>(hidden, gate, out, accum);
  router_loss_kernel<<<1, 64, 0, stream>>>(accum, out);
}

// Round 4
// 99.277 us; speedup vs baseline: 5.6888x; 1.7968x over previous
//
#include <hip/hip_runtime.h>

#define TOKENS 16384
#define HDIM   4096
#define KPARTS 8
#define KPW    (HDIM / KPARTS)     // 512 k per wave
#define NCHK   (KPW / 32)          // 16 chunks of 32 k per wave

typedef __attribute__((ext_vector_type(8))) short bf16x8;
typedef __attribute__((ext_vector_type(4))) float f32x4;

union PKU { unsigned int u[4]; int4 i4; bf16x8 v; };

__device__ __forceinline__ float4 L(const float* p) {
  return *reinterpret_cast<const float4*>(p);
}

// Exact 3-way bf16 split of 8 fp32: x = h + m + l (+O(2^-24 x) truncation)
__device__ __forceinline__ void split8(const float4 a, const float4 b,
                                       int4& h4, int4& m4, int4& l4) {
  const float e[8] = {a.x, a.y, a.z, a.w, b.x, b.y, b.z, b.w};
  unsigned int hb[8], mb[8], lb[8];
#pragma unroll
  for (int i = 0; i < 8; ++i) {
    const unsigned int xb = __float_as_uint(e[i]);
    hb[i] = xb & 0xFFFF0000u;
    const float r = e[i] - __uint_as_float(hb[i]);
    const unsigned int rb = __float_as_uint(r);
    mb[i] = rb & 0xFFFF0000u;
    const float r2 = r - __uint_as_float(mb[i]);
    lb[i] = __float_as_uint(r2);
  }
  PKU h, m, l;
#pragma unroll
  for (int j = 0; j < 4; ++j) {
    h.u[j] = (hb[2*j] >> 16) | (hb[2*j+1] & 0xFFFF0000u);
    m.u[j] = (mb[2*j] >> 16) | (mb[2*j+1] & 0xFFFF0000u);
    l.u[j] = (lb[2*j] >> 16) | (lb[2*j+1] & 0xFFFF0000u);
  }
  h4 = h.i4; m4 = m.i4; l4 = l.i4;
}

__device__ __forceinline__ bf16x8 asbf(const int4 x) { PKU u; u.i4 = x; return u.v; }

#define MFMA6(ACC, AH, AM, AL, BH, BM, BL)                                     \
  ACC = __builtin_amdgcn_mfma_f32_16x16x32_bf16(AH, BH, ACC, 0, 0, 0);         \
  ACC = __builtin_amdgcn_mfma_f32_16x16x32_bf16(AM, BH, ACC, 0, 0, 0);         \
  ACC = __builtin_amdgcn_mfma_f32_16x16x32_bf16(AH, BM, ACC, 0, 0, 0);         \
  ACC = __builtin_amdgcn_mfma_f32_16x16x32_bf16(AL, BH, ACC, 0, 0, 0);         \
  ACC = __builtin_amdgcn_mfma_f32_16x16x32_bf16(AH, BL, ACC, 0, 0, 0);         \
  ACC = __builtin_amdgcn_mfma_f32_16x16x32_bf16(AM, BM, ACC, 0, 0, 0);

// Pre-split gate into bf16 h/m/l fragment planes, MFMA layout:
// wsB[((cg*4+nt)*3+p)*64 + lane] = 16B fragment, cg=0..127 global 32-k chunk.
__global__ void prep_gate_kernel(const float* __restrict__ gate,
                                 int4* __restrict__ wsB) {
  const int lane  = threadIdx.x & 63;
  const int cg    = blockIdx.x >> 2;
  const int nt    = blockIdx.x & 3;
  const int col16 = lane & 15, kq = lane >> 4;
  const float* gp = gate + (size_t)(nt * 16 + col16) * HDIM + cg * 32 + kq * 8;
  int4 h, m, l;
  split8(L(gp), L(gp + 4), h, m, l);
  int4* p = wsB + ((size_t)(cg * 4 + nt) * 3) * 64 + lane;
  p[0] = h; p[64] = m; p[128] = l;
}

template <int PRE>
__global__ __launch_bounds__(512, 4)
void router_main_kernel(const float* __restrict__ hidden,
                        const float* __restrict__ gate,
                        const int4* __restrict__ wsB,
                        float* __restrict__ out,
                        float* __restrict__ accum) {
  __shared__ f32x4 comb[4 * 8 * 64];   // 32 KB tree-reduce buffer

  const int tid   = threadIdx.x;
  const int lane  = tid & 63;
  const int wave  = tid >> 6;          // k-part 0..7
  const int col16 = lane & 15;
  const int kq    = lane >> 4;
  const int tok0  = blockIdx.x * 32;

  const float* aP0 = hidden + (size_t)(tok0 + col16) * HDIM + wave * KPW + kq * 8;
  const float* aP1 = aP0 + (size_t)16 * HDIM;

  f32x4 acc[2][4];
#pragma unroll
  for (int f = 0; f < 2; ++f)
#pragma unroll
    for (int nt = 0; nt < 4; ++nt) acc[f][nt] = (f32x4){0.f, 0.f, 0.f, 0.f};

  bf16x8 bh[4], bm[4], bl[4];

  auto loadB = [&](int c, int nt) {
    if (PRE) {
      const int cg = wave * NCHK + c;
      const int4* p = wsB + ((size_t)(cg * 4 + nt) * 3) * 64 + lane;
      bh[nt] = asbf(p[0]); bm[nt] = asbf(p[64]); bl[nt] = asbf(p[128]);
    } else {
      const float* gp = gate + (size_t)(nt * 16 + col16) * HDIM + wave * KPW + c * 32 + kq * 8;
      int4 h4, m4, l4;
      split8(L(gp), L(gp + 4), h4, m4, l4);
      bh[nt] = asbf(h4); bm[nt] = asbf(m4); bl[nt] = asbf(l4);
    }
  };

  float4 a0[2], a1[2];
  a0[0] = L(aP0); a0[1] = L(aP0 + 4);
  a1[0] = L(aP1); a1[1] = L(aP1 + 4);
#pragma unroll
  for (int nt = 0; nt < 4; ++nt) loadB(0, nt);

  for (int c = 0; c < NCHK; ++c) {
    const int nko = (c + 1) * 32;
    int4 h4, m4, l4;
    // ---- fragment 0 ----
    split8(a0[0], a0[1], h4, m4, l4);
    bf16x8 ah = asbf(h4), am = asbf(m4), al = asbf(l4);
    if (c + 1 < NCHK) { a0[0] = L(aP0 + nko); a0[1] = L(aP0 + nko + 4); }
#pragma unroll
    for (int nt = 0; nt < 4; ++nt) {
      MFMA6(acc[0][nt], ah, am, al, bh[nt], bm[nt], bl[nt]);
    }
    // ---- fragment 1 ----
    split8(a1[0], a1[1], h4, m4, l4);
    ah = asbf(h4); am = asbf(m4); al = asbf(l4);
    if (c + 1 < NCHK) { a1[0] = L(aP1 + nko); a1[1] = L(aP1 + nko + 4); }
#pragma unroll
    for (int nt = 0; nt < 4; ++nt) {
      MFMA6(acc[1][nt], ah, am, al, bh[nt], bm[nt], bl[nt]);
      if (c + 1 < NCHK) loadB(c + 1, nt);   // rolling reload after last use
    }
  }

  // ---- tree-reduce the 8 K-parts (conflict-free [slot][fnt][lane] layout) --
#pragma unroll
  for (int step = 4; step >= 1; step >>= 1) {
    if (wave >= step && wave < 2 * step) {
      const int base = (wave - step) * 8 * 64 + lane;
#pragma unroll
      for (int f = 0; f < 2; ++f)
#pragma unroll
        for (int nt = 0; nt < 4; ++nt) comb[base + (f * 4 + nt) * 64] = acc[f][nt];
    }
    __syncthreads();
    if (wave < step) {
      const int base = wave * 8 * 64 + lane;
#pragma unroll
      for (int f = 0; f < 2; ++f)
#pragma unroll
        for (int nt = 0; nt < 4; ++nt) acc[f][nt] += comb[base + (f * 4 + nt) * 64];
    }
    __syncthreads();
  }

  // ---- wave 0: top-2 + softmax + stats for 32 tokens ----
  if (wave == 0) {
    float* out_w = out;
    float* out_e = out + (size_t)TOKENS * 2;
    float psum[4] = {0.f, 0.f, 0.f, 0.f};
    float cnt[4]  = {0.f, 0.f, 0.f, 0.f};

#pragma unroll
    for (int f = 0; f < 2; ++f) {
#pragma unroll
      for (int r = 0; r < 4; ++r) {
        const int tok = tok0 + f * 16 + kq * 4 + r;
        float v1 = acc[f][0][r]; int i1 = col16;
        float v2 = -3.4e38f;     int i2 = 1 << 30;
#pragma unroll
        for (int nt = 1; nt < 4; ++nt) {
          const float v = acc[f][nt][r]; const int ix = nt * 16 + col16;
          if (v > v1)      { v2 = v1; i2 = i1; v1 = v; i1 = ix; }
          else if (v > v2) { v2 = v;  i2 = ix; }
        }
#pragma unroll
        for (int m = 1; m < 16; m <<= 1) {
          const float ov1 = __shfl_xor(v1, m, 64); const int oi1 = __shfl_xor(i1, m, 64);
          const float ov2 = __shfl_xor(v2, m, 64); const int oi2 = __shfl_xor(i2, m, 64);
          const bool  ob  = (ov1 > v1) || (ov1 == v1 && oi1 < i1);
          const float lv  = ob ? v1  : ov1;  const int li = ob ? i1  : oi1;
          const float rv  = ob ? ov2 : v2;   const int ri = ob ? oi2 : i2;
          v1 = ob ? ov1 : v1; i1 = ob ? oi1 : i1;
          const bool  ab  = (lv > rv) || (lv == rv && li < ri);
          v2 = ab ? lv : rv;  i2 = ab ? li : ri;
        }
        float el[4], ls = 0.f;
#pragma unroll
        for (int nt = 0; nt < 4; ++nt) { el[nt] = expf(acc[f][nt][r] - v1); ls += el[nt]; }
#pragma unroll
        for (int m = 1; m < 16; m <<= 1) ls += __shfl_xor(ls, m, 64);
        const float inv = 1.f / ls;
#pragma unroll
        for (int nt = 0; nt < 4; ++nt) {
          psum[nt] += el[nt] * inv;
          cnt[nt]  += (i1 == nt * 16 + col16) + (i2 == nt * 16 + col16);
        }
        if (col16 == 0) {
          const float e2 = expf(v2 - v1);
          const float w1 = 1.f / (1.f + e2);
          out_w[tok * 2 + 0] = w1;
          out_w[tok * 2 + 1] = e2 * w1;
          out_e[tok * 2 + 0] = (float)i1;
          out_e[tok * 2 + 1] = (float)i2;
        }
      }
    }
#pragma unroll
    for (int nt = 0; nt < 4; ++nt) {
      psum[nt] += __shfl_xor(psum[nt], 16, 64);
      psum[nt] += __shfl_xor(psum[nt], 32, 64);
      cnt[nt]  += __shfl_xor(cnt[nt], 16, 64);
      cnt[nt]  += __shfl_xor(cnt[nt], 32, 64);
    }
    if (lane < 16) {
#pragma unroll
      for (int nt = 0; nt < 4; ++nt) {
        atomicAdd(&accum[nt * 16 + lane], psum[nt]);
        atomicAdd(&accum[64 + nt * 16 + lane], cnt[nt]);
      }
    }
  }
}

__global__ void zero_accum_kernel(float* __restrict__ accum) {
  if (threadIdx.x < 128) accum[threadIdx.x] = 0.f;
}

__global__ void router_loss_kernel(const float* __restrict__ accum,
                                   float* __restrict__ out) {
  const int l = threadIdx.x;  // 64 threads
  float term = accum[l] * accum[64 + l];   // P_sum_e * count_e
#pragma unroll
  for (int m = 1; m < 64; m <<= 1) term += __shfl_xor(term, m, 64);
  if (l == 0) {
    const float invN = 1.f / (float)TOKENS;
    out[(size_t)TOKENS * 4] = 0.01f * 64.f * term * invN * invN;
  }
}

extern "C" void kernel_launch(void* const* d_in, const int* in_sizes, int n_in,
                              void* d_out, int out_size, void* d_ws, size_t ws_size,
                              hipStream_t stream) {
  const float* hidden = (const float*)d_in[0];  // [4,4096,4096] f32
  const float* gate   = (const float*)d_in[1];  // [64,4096] f32
  float* out   = (float*)d_out;                 // 32768 w + 32768 idx + 1 loss
  float* accum = (float*)d_ws;                  // 128 floats
  int4*  wsB   = (int4*)((char*)d_ws + 512);    // 1.5 MB gate planes

  const size_t need = 512 + (size_t)128 * 4 * 3 * 64 * sizeof(int4);
  zero_accum_kernel<<<1, 128, 0, stream>>>(accum);
  if (ws_size >= need) {
    prep_gate_kernel<<<512, 64, 0, stream>>>(gate, wsB);
    router_main_kernel<1><<<TOKENS / 32, 512, 0, stream>>>(hidden, gate, wsB, out, accum);
  } else {
    router_main_kernel<0><<<TOKENS / 32, 512, 0, stream>>>(hidden, gate, wsB, out, accum);
  }
  router_loss_kernel<<<1, 64, 0, stream>>>(accum, out);
}

// Round 5
// 92.262 us; speedup vs baseline: 6.1214x; 1.0760x over previous
//
#include <hip/hip_runtime.h>

#define TOKENS 16384
#define HDIM   4096
#define NPARTS 8
#define KPW    (HDIM / NPARTS)      // 512 k per K-part
#define NCHK   (KPW / 32)           // 16 chunks per part
#define CHU    768                  // int4 units per chunk (4nt x 3 planes x 64)

typedef __attribute__((ext_vector_type(8))) short bf16x8;
typedef __attribute__((ext_vector_type(4))) float f32x4;

union PKU { unsigned int u[4]; int4 i4; bf16x8 v; };

__device__ __forceinline__ float4 L(const float* p) {
  return *reinterpret_cast<const float4*>(p);
}

// Exact 3-way bf16 split of 8 fp32: x = h + m + l (+O(2^-24 x) truncation)
__device__ __forceinline__ void split8(const float4 a, const float4 b,
                                       int4& h4, int4& m4, int4& l4) {
  const float e[8] = {a.x, a.y, a.z, a.w, b.x, b.y, b.z, b.w};
  unsigned int hb[8], mb[8], lb[8];
#pragma unroll
  for (int i = 0; i < 8; ++i) {
    const unsigned int xb = __float_as_uint(e[i]);
    hb[i] = xb & 0xFFFF0000u;
    const float r = e[i] - __uint_as_float(hb[i]);
    const unsigned int rb = __float_as_uint(r);
    mb[i] = rb & 0xFFFF0000u;
    const float r2 = r - __uint_as_float(mb[i]);
    lb[i] = __float_as_uint(r2);
  }
  PKU h, m, l;
#pragma unroll
  for (int j = 0; j < 4; ++j) {
    h.u[j] = (hb[2*j] >> 16) | (hb[2*j+1] & 0xFFFF0000u);
    m.u[j] = (mb[2*j] >> 16) | (mb[2*j+1] & 0xFFFF0000u);
    l.u[j] = (lb[2*j] >> 16) | (lb[2*j+1] & 0xFFFF0000u);
  }
  h4 = h.i4; m4 = m.i4; l4 = l.i4;
}

__device__ __forceinline__ bf16x8 asbf(const int4 x) { PKU u; u.i4 = x; return u.v; }

#define MFMA6(ACC, AH, AM, AL, BH, BM, BL)                                     \
  ACC = __builtin_amdgcn_mfma_f32_16x16x32_bf16(AH, BH, ACC, 0, 0, 0);         \
  ACC = __builtin_amdgcn_mfma_f32_16x16x32_bf16(AM, BH, ACC, 0, 0, 0);         \
  ACC = __builtin_amdgcn_mfma_f32_16x16x32_bf16(AH, BM, ACC, 0, 0, 0);         \
  ACC = __builtin_amdgcn_mfma_f32_16x16x32_bf16(AL, BH, ACC, 0, 0, 0);         \
  ACC = __builtin_amdgcn_mfma_f32_16x16x32_bf16(AH, BL, ACC, 0, 0, 0);         \
  ACC = __builtin_amdgcn_mfma_f32_16x16x32_bf16(AM, BM, ACC, 0, 0, 0);

__device__ __forceinline__ void load_lds16(const float* g, float* l) {
  __builtin_amdgcn_global_load_lds(
      (const __attribute__((address_space(1))) void*)g,
      (__attribute__((address_space(3))) void*)l, 16, 0, 0);
}

// Pre-split gate into bf16 h/m/l planes, laid out chunk-contiguous:
// wsB[(part*16+ch)*768 + (nt*3+plane)*64 + lane]
__global__ void prep_gate_kernel(const float* __restrict__ gate,
                                 int4* __restrict__ wsB) {
  const int c    = blockIdx.x;          // part*16 + chunk
  const int tid  = threadIdx.x;         // 256
  const int lane = tid & 63, nt = tid >> 6;
  const int col16 = lane & 15, kq = lane >> 4;
  const int k = (c >> 4) * KPW + (c & 15) * 32 + kq * 8;
  const float* gp = gate + (size_t)(nt * 16 + col16) * HDIM + k;
  int4 h, m, l;
  split8(L(gp), L(gp + 4), h, m, l);
  int4* dst = wsB + (size_t)c * CHU + nt * 3 * 64 + lane;
  dst[0] = h; dst[64] = m; dst[128] = l;
}

__global__ __launch_bounds__(512, 4)
void router_gemm_kernel(const float* __restrict__ hidden,
                        const int4* __restrict__ wsB,
                        float* __restrict__ pw) {
  __shared__ int4 bbuf[2][CHU];         // 24 KB double-buffered B planes

  const int tid   = threadIdx.x;
  const int lane  = tid & 63;
  const int wave  = tid >> 6;
  const int col16 = lane & 15;
  const int kq    = lane >> 4;
  const int part  = blockIdx.x & 7;     // fast dim -> pinned XCD for B slice
  const int tg    = blockIdx.x >> 3;
  const int tok0  = tg * 256 + wave * 32;

  const float* aP0 = hidden + (size_t)(tok0 + col16) * HDIM + part * KPW + kq * 8;
  const float* aP1 = aP0 + (size_t)16 * HDIM;
  const int4* wsrc = wsB + (size_t)part * NCHK * CHU;

  f32x4 acc0[4], acc1[4];
#pragma unroll
  for (int nt = 0; nt < 4; ++nt) {
    acc0[nt] = (f32x4){0.f, 0.f, 0.f, 0.f};
    acc1[nt] = (f32x4){0.f, 0.f, 0.f, 0.f};
  }

  auto stage = [&](int c, int bi) {
    const int4* s = wsrc + c * CHU;
    load_lds16((const float*)(s + wave * 64 + lane), (float*)&bbuf[bi][wave * 64]);
    if (tid < 256)
      load_lds16((const float*)(s + 512 + wave * 64 + lane),
                 (float*)&bbuf[bi][512 + wave * 64]);
  };

  float4 a00 = L(aP0),     a01 = L(aP0 + 4);
  float4 a10 = L(aP1),     a11 = L(aP1 + 4);
  stage(0, 0);
  __syncthreads();                       // drains vmcnt: buf0 + A(0) ready

#pragma unroll 1
  for (int c = 0; c < NCHK; ++c) {
    const int cur = c & 1;
    if (c + 1 < NCHK) stage(c + 1, cur ^ 1);
    float4 n00, n01, n10, n11;
    if (c + 1 < NCHK) {
      const int ko = (c + 1) * 32;
      n00 = L(aP0 + ko); n01 = L(aP0 + ko + 4);
      n10 = L(aP1 + ko); n11 = L(aP1 + ko + 4);
    }
    int4 h4, m4, l4;
    split8(a00, a01, h4, m4, l4);
    const bf16x8 a0h = asbf(h4), a0m = asbf(m4), a0l = asbf(l4);
    split8(a10, a11, h4, m4, l4);
    const bf16x8 a1h = asbf(h4), a1m = asbf(m4), a1l = asbf(l4);
#pragma unroll
    for (int nt = 0; nt < 4; ++nt) {
      const bf16x8 bh = asbf(bbuf[cur][(nt * 3 + 0) * 64 + lane]);
      const bf16x8 bm = asbf(bbuf[cur][(nt * 3 + 1) * 64 + lane]);
      const bf16x8 bl = asbf(bbuf[cur][(nt * 3 + 2) * 64 + lane]);
      MFMA6(acc0[nt], a0h, a0m, a0l, bh, bm, bl);
      MFMA6(acc1[nt], a1h, a1m, a1l, bh, bm, bl);
    }
    __syncthreads();                     // buf[cur] consumed; stage(c+1) landed
    a00 = n00; a01 = n01; a10 = n10; a11 = n11;
  }

  // partials[part][tok][e]
  float* prow = pw + (size_t)part * TOKENS * 64;
#pragma unroll
  for (int f = 0; f < 2; ++f)
#pragma unroll
    for (int nt = 0; nt < 4; ++nt)
#pragma unroll
      for (int r = 0; r < 4; ++r) {
        const int tok = tok0 + f * 16 + kq * 4 + r;
        prow[(size_t)tok * 64 + nt * 16 + col16] = f ? acc1[nt][r] : acc0[nt][r];
      }
}

__global__ __launch_bounds__(256, 4)
void router_top2_kernel(const float* __restrict__ pw,
                        float* __restrict__ out,
                        float* __restrict__ accum) {
  __shared__ float red[2][4][4][16];     // [psum/cnt][wave][slice][16]

  const int tid  = threadIdx.x;
  const int lane = tid & 63, wave = tid >> 6;
  const int tok  = blockIdx.x * 64 + wave * 16 + (lane >> 2);
  const int sl   = lane & 3;             // expert slice: e in [sl*16, sl*16+16)

  f32x4 s[4];
#pragma unroll
  for (int q = 0; q < 4; ++q) s[q] = (f32x4){0.f, 0.f, 0.f, 0.f};
#pragma unroll
  for (int p = 0; p < NPARTS; ++p) {
    const float* b = pw + ((size_t)p * TOKENS + tok) * 64 + sl * 16;
#pragma unroll
    for (int q = 0; q < 4; ++q) {
      const float4 v = L(b + q * 4);
      s[q][0] += v.x; s[q][1] += v.y; s[q][2] += v.z; s[q][3] += v.w;
    }
  }

  // in-lane top-2 over 16 experts, ascending index (tie -> lower)
  float v1 = s[0][0]; int i1 = sl * 16;
  float v2 = -3.4e38f; int i2 = 1 << 30;
#pragma unroll
  for (int q = 0; q < 4; ++q)
#pragma unroll
    for (int j = 0; j < 4; ++j) {
      if (q == 0 && j == 0) continue;
      const float v = s[q][j]; const int ix = sl * 16 + q * 4 + j;
      if (v > v1)      { v2 = v1; i2 = i1; v1 = v; i1 = ix; }
      else if (v > v2) { v2 = v;  i2 = ix; }
    }
  // merge across the 4 slice-lanes of this token
#pragma unroll
  for (int m = 1; m < 4; m <<= 1) {
    const float ov1 = __shfl_xor(v1, m, 64); const int oi1 = __shfl_xor(i1, m, 64);
    const float ov2 = __shfl_xor(v2, m, 64); const int oi2 = __shfl_xor(i2, m, 64);
    const bool  ob  = (ov1 > v1) || (ov1 == v1 && oi1 < i1);
    const float lv  = ob ? v1  : ov1;  const int li = ob ? i1  : oi1;
    const float rv  = ob ? ov2 : v2;   const int ri = ob ? oi2 : i2;
    v1 = ob ? ov1 : v1; i1 = ob ? oi1 : i1;
    const bool  ab  = (lv > rv) || (lv == rv && li < ri);
    v2 = ab ? lv : rv;  i2 = ab ? li : ri;
  }
  // full softmax over 64 experts (v1 = true max in all 4 lanes)
  float el[16]; float ls = 0.f;
#pragma unroll
  for (int q = 0; q < 4; ++q)
#pragma unroll
    for (int j = 0; j < 4; ++j) { el[q*4+j] = expf(s[q][j] - v1); ls += el[q*4+j]; }
#pragma unroll
  for (int m = 1; m < 4; m <<= 1) ls += __shfl_xor(ls, m, 64);
  const float inv = 1.f / ls;

  float psum[16], cnt[16];
#pragma unroll
  for (int j = 0; j < 16; ++j) {
    psum[j] = el[j] * inv;
    const int ix = sl * 16 + j;
    cnt[j] = (float)((i1 == ix) + (i2 == ix));
  }

  if (sl == 0) {
    const float e2 = expf(v2 - v1);
    const float w1 = 1.f / (1.f + e2);
    out[tok * 2 + 0] = w1;
    out[tok * 2 + 1] = e2 * w1;
    out[(size_t)TOKENS * 2 + tok * 2 + 0] = (float)i1;
    out[(size_t)TOKENS * 2 + tok * 2 + 1] = (float)i2;
  }

  // per-expert stats: reduce over the 16 tokens of this wave (stride-4 lanes)
#pragma unroll
  for (int m = 4; m < 64; m <<= 1)
#pragma unroll
    for (int j = 0; j < 16; ++j) {
      psum[j] += __shfl_xor(psum[j], m, 64);
      cnt[j]  += __shfl_xor(cnt[j], m, 64);
    }
  if (lane < 4) {
#pragma unroll
    for (int j = 0; j < 16; ++j) {
      red[0][wave][sl][j] = psum[j];
      red[1][wave][sl][j] = cnt[j];
    }
  }
  __syncthreads();
  if (tid < 64) {
    const int sl2 = tid >> 4, j2 = tid & 15;
    float ps = 0.f, cs = 0.f;
#pragma unroll
    for (int w = 0; w < 4; ++w) { ps += red[0][w][sl2][j2]; cs += red[1][w][sl2][j2]; }
    atomicAdd(&accum[sl2 * 16 + j2], ps);
    atomicAdd(&accum[64 + sl2 * 16 + j2], cs);
  }
}

__global__ void zero_accum_kernel(float* __restrict__ accum) {
  if (threadIdx.x < 128) accum[threadIdx.x] = 0.f;
}

__global__ void router_loss_kernel(const float* __restrict__ accum,
                                   float* __restrict__ out) {
  const int l = threadIdx.x;  // 64 threads
  float term = accum[l] * accum[64 + l];   // P_sum_e * count_e
#pragma unroll
  for (int m = 1; m < 64; m <<= 1) term += __shfl_xor(term, m, 64);
  if (l == 0) {
    const float invN = 1.f / (float)TOKENS;
    out[(size_t)TOKENS * 4] = 0.01f * 64.f * term * invN * invN;
  }
}

extern "C" void kernel_launch(void* const* d_in, const int* in_sizes, int n_in,
                              void* d_out, int out_size, void* d_ws, size_t ws_size,
                              hipStream_t stream) {
  const float* hidden = (const float*)d_in[0];  // [4,4096,4096] f32
  const float* gate   = (const float*)d_in[1];  // [64,4096] f32
  float* out   = (float*)d_out;                 // 32768 w + 32768 idx + 1 loss

  float* accum = (float*)d_ws;                                   // 128 f32
  int4*  wsB   = (int4*)((char*)d_ws + 1024);                    // 1.5 MB planes
  float* pw    = (float*)((char*)d_ws + 1024 + 1572864);         // 33.5 MB partials

  zero_accum_kernel<<<1, 128, 0, stream>>>(accum);
  prep_gate_kernel<<<NPARTS * NCHK, 256, 0, stream>>>(gate, wsB);
  router_gemm_kernel<<<(TOKENS / 256) * NPARTS, 512, 0, stream>>>(hidden, wsB, pw);
  router_top2_kernel<<<TOKENS / 64, 256, 0, stream>>>(pw, out, accum);
  router_loss_kernel<<<1, 64, 0, stream>>>(accum, out);
}